// Round 1
// baseline (7308.348 us; speedup 1.0000x reference)
//
#include <hip/hip_runtime.h>
#include <math.h>

#define NNODES 5000
#define NEDGES 80000
#define NB 8
#define NIN 30
#define NH 4
#define ND 64
#define NHD 256
#define NT 5
#define NOUT 3
#define ROWS (NB * NNODES) // 40000
#define BNEPS 1e-5f

// ---------------- CSR build ----------------

__global__ void count_kernel(const int* __restrict__ dst, int* __restrict__ counts, int n) {
    int e = blockIdx.x * blockDim.x + threadIdx.x;
    if (e < n) atomicAdd(&counts[dst[e]], 1);
}

__global__ __launch_bounds__(1024) void scan_kernel(const int* __restrict__ counts,
                                                    int* __restrict__ offsets, int n) {
    __shared__ int smem[1024];
    const int CH = 5; // 1024*5 >= 5000
    int tid = threadIdx.x;
    int base = tid * CH;
    int loc[CH];
    int s = 0;
    for (int j = 0; j < CH; ++j) {
        int i = base + j;
        int v = (i < n) ? counts[i] : 0;
        loc[j] = s;
        s += v;
    }
    smem[tid] = s;
    __syncthreads();
    for (int off = 1; off < 1024; off <<= 1) {
        int v = (tid >= off) ? smem[tid - off] : 0;
        __syncthreads();
        smem[tid] += v;
        __syncthreads();
    }
    int excl = smem[tid] - s;
    for (int j = 0; j < CH; ++j) {
        int i = base + j;
        if (i < n) offsets[i] = excl + loc[j];
    }
    if (tid == 1023) offsets[n] = smem[1023];
}

__global__ void fill_kernel(const int* __restrict__ src, const int* __restrict__ dst,
                            const int* __restrict__ offsets, int* __restrict__ cursor,
                            int* __restrict__ csr_src, int n) {
    int e = blockIdx.x * blockDim.x + threadIdx.x;
    if (e >= n) return;
    int d = dst[e];
    int pos = offsets[d] + atomicAdd(&cursor[d], 1);
    csr_src[pos] = src[e];
}

// ---------------- GEMM: C[M,256] = A[M,K] @ W[K,256] ----------------
// BM=64 BN=64 BK=16, 256 threads, 4x4 microtile. M % 64 == 0, N = 256.

__global__ __launch_bounds__(256) void gemm_kernel(const float* __restrict__ A,
                                                   const float* __restrict__ W,
                                                   float* __restrict__ C, int K) {
    __shared__ float As[16][65];
    __shared__ float Bs[16][65];
    int tid = threadIdx.x;
    int tx = tid & 15;
    int ty = tid >> 4;
    int row0 = blockIdx.x * 64;
    int col0 = blockIdx.y * 64;
    float acc[4][4] = {};
    for (int k0 = 0; k0 < K; k0 += 16) {
        // load A tile 64x16
        for (int i = tid; i < 64 * 16; i += 256) {
            int m = i >> 4;
            int k = i & 15;
            float v = (k0 + k < K) ? A[(size_t)(row0 + m) * K + k0 + k] : 0.0f;
            As[k][m] = v;
        }
        // load W tile 16x64
        for (int i = tid; i < 16 * 64; i += 256) {
            int k = i >> 6;
            int n = i & 63;
            float v = (k0 + k < K) ? W[(size_t)(k0 + k) * NHD + col0 + n] : 0.0f;
            Bs[k][n] = v;
        }
        __syncthreads();
#pragma unroll
        for (int k = 0; k < 16; ++k) {
            float a[4], b[4];
#pragma unroll
            for (int i = 0; i < 4; ++i) a[i] = As[k][ty * 4 + i];
#pragma unroll
            for (int j = 0; j < 4; ++j) b[j] = Bs[k][tx * 4 + j];
#pragma unroll
            for (int i = 0; i < 4; ++i)
#pragma unroll
                for (int j = 0; j < 4; ++j) acc[i][j] += a[i] * b[j];
        }
        __syncthreads();
    }
#pragma unroll
    for (int i = 0; i < 4; ++i)
#pragma unroll
        for (int j = 0; j < 4; ++j)
            C[(size_t)(row0 + ty * 4 + i) * NHD + col0 + tx * 4 + j] = acc[i][j];
}

// ---------------- attention logits el/er ----------------
// block = 256 (4 waves), blockIdx = b*N+n, wave = head

__global__ __launch_bounds__(256) void eler_kernel(const float* __restrict__ h,
                                                   const float* __restrict__ al,
                                                   const float* __restrict__ ar,
                                                   float* __restrict__ el,
                                                   float* __restrict__ er) {
    int g = blockIdx.x;
    int head = threadIdx.x >> 6;
    int lane = threadIdx.x & 63;
    float hv = h[(size_t)g * NHD + head * ND + lane];
    float pl = hv * al[head * ND + lane];
    float pr = hv * ar[head * ND + lane];
    for (int o = 32; o; o >>= 1) {
        pl += __shfl_xor(pl, o);
        pr += __shfl_xor(pr, o);
    }
    if (lane == 0) {
        el[g * NH + head] = pl;
        er[g * NH + head] = pr;
    }
}

// ---------------- edge softmax + aggregate (CSR, no atomics) ----------------
// block = 256 (4 waves = 4 heads), blockIdx = b*N+n

__global__ __launch_bounds__(256) void attn_kernel(const float* __restrict__ h,
                                                   const float* __restrict__ el,
                                                   const float* __restrict__ er,
                                                   const int* __restrict__ offsets,
                                                   const int* __restrict__ csr_src,
                                                   float* __restrict__ out) {
    int g = blockIdx.x; // b*N + n
    int b = g / NNODES;
    int n = g - b * NNODES;
    int head = threadIdx.x >> 6;
    int lane = threadIdx.x & 63;
    int start = offsets[n];
    int end = offsets[n + 1];
    const float* elb = el + (size_t)b * NNODES * NH;
    float er_nh = er[(size_t)g * NH + head];

    // pass 1: max over incoming edges
    float mx = -INFINITY;
    for (int i = start + lane; i < end; i += 64) {
        int s = csr_src[i];
        float e = elb[s * NH + head] + er_nh;
        e = (e > 0.0f) ? e : 0.2f * e;
        mx = fmaxf(mx, e);
    }
    for (int o = 32; o; o >>= 1) mx = fmaxf(mx, __shfl_xor(mx, o));

    // pass 2: sum of exp
    float sm = 0.0f;
    for (int i = start + lane; i < end; i += 64) {
        int s = csr_src[i];
        float e = elb[s * NH + head] + er_nh;
        e = (e > 0.0f) ? e : 0.2f * e;
        sm += expf(e - mx);
    }
    for (int o = 32; o; o >>= 1) sm += __shfl_xor(sm, o);

    // pass 3: weighted gather-sum over feature dim (lane = d)
    const float* hb = h + (size_t)b * NNODES * NHD;
    float acc = 0.0f;
    for (int i = start; i < end; ++i) {
        int s = csr_src[i];
        float e = elb[s * NH + head] + er_nh;
        e = (e > 0.0f) ? e : 0.2f * e;
        float w = expf(e - mx);
        acc += w * hb[(size_t)s * NHD + head * ND + lane];
    }
    float inv = (end > start) ? 1.0f / sm : 0.0f;
    out[(size_t)g * NHD + head * ND + lane] = acc * inv;
}

// ---------------- BatchNorm reduce ----------------
// thread = channel; block strides rows. sums[0:256]=sum, sums[256:512]=sumsq

__global__ __launch_bounds__(256) void bnreduce_kernel(const float* __restrict__ x,
                                                       float* __restrict__ sums) {
    int c = threadIdx.x;
    float s = 0.0f, s2 = 0.0f;
    for (int row = blockIdx.x; row < ROWS; row += gridDim.x) {
        float v = x[(size_t)row * NHD + c];
        s += v;
        s2 += v * v;
    }
    atomicAdd(&sums[c], s);
    atomicAdd(&sums[NHD + c], s2);
}

__global__ __launch_bounds__(256) void bnapply_kernel(float* __restrict__ x,
                                                      const float* __restrict__ sums,
                                                      const float* __restrict__ gamma,
                                                      const float* __restrict__ beta) {
    int c = threadIdx.x;
    int row = blockIdx.x;
    const float invn = 1.0f / (float)ROWS;
    float mu = sums[c] * invn;
    float var = sums[NHD + c] * invn - mu * mu;
    float sc = rsqrtf(var + BNEPS) * gamma[c];
    float bt = beta[c];
    float v = x[(size_t)row * NHD + c];
    v = (v - mu) * sc + bt;
    v = (v > 0.0f) ? v : 0.01f * v;
    x[(size_t)row * NHD + c] = v;
}

// ---------------- output head + window shift ----------------
// block = 256 (4 waves), each wave handles one (b,n). t = rollout step.

__global__ __launch_bounds__(256) void headout_kernel(const float* __restrict__ x,
                                                      const float* __restrict__ Wout,
                                                      const float* __restrict__ bout,
                                                      float* __restrict__ out,
                                                      float* __restrict__ xx_cur, int t) {
    int wave = threadIdx.x >> 6;
    int lane = threadIdx.x & 63;
    int g = blockIdx.x * 4 + wave; // b*N + n
    const float* xr = x + (size_t)g * NHD;
    int c0 = lane * 4;
    float4 v = *(const float4*)(xr + c0);
    float r0 = v.x * Wout[(c0 + 0) * NOUT + 0] + v.y * Wout[(c0 + 1) * NOUT + 0] +
               v.z * Wout[(c0 + 2) * NOUT + 0] + v.w * Wout[(c0 + 3) * NOUT + 0];
    float r1 = v.x * Wout[(c0 + 0) * NOUT + 1] + v.y * Wout[(c0 + 1) * NOUT + 1] +
               v.z * Wout[(c0 + 2) * NOUT + 1] + v.w * Wout[(c0 + 3) * NOUT + 1];
    float r2 = v.x * Wout[(c0 + 0) * NOUT + 2] + v.y * Wout[(c0 + 1) * NOUT + 2] +
               v.z * Wout[(c0 + 2) * NOUT + 2] + v.w * Wout[(c0 + 3) * NOUT + 2];
    for (int o = 32; o; o >>= 1) {
        r0 += __shfl_xor(r0, o);
        r1 += __shfl_xor(r1, o);
        r2 += __shfl_xor(r2, o);
    }
    float o0 = r0 + bout[0], o1 = r1 + bout[1], o2 = r2 + bout[2];
    if (lane == 0) {
        float* op = out + ((size_t)g * NT + t) * NOUT;
        op[0] = o0;
        op[1] = o1;
        op[2] = o2;
    }
    // shift input window: new[0:27] = old[3:30]; new[27:30] = o
    float oldv = (lane < NIN) ? xx_cur[(size_t)g * NIN + lane] : 0.0f;
    float shifted = __shfl(oldv, lane + 3);
    float newv = (lane < 27) ? shifted : (lane == 27 ? o0 : (lane == 28 ? o1 : o2));
    if (lane < NIN) xx_cur[(size_t)g * NIN + lane] = newv;
}

// ---------------- launch ----------------

extern "C" void kernel_launch(void* const* d_in, const int* in_sizes, int n_in,
                              void* d_out, int out_size, void* d_ws, size_t ws_size,
                              hipStream_t stream) {
    const float* xx = (const float*)d_in[0];
    const int* src = (const int*)d_in[1];
    const int* dst = (const int*)d_in[2];
    const float* W[4] = {(const float*)d_in[3], (const float*)d_in[8],
                         (const float*)d_in[13], (const float*)d_in[18]};
    const float* al[4] = {(const float*)d_in[4], (const float*)d_in[9],
                          (const float*)d_in[14], (const float*)d_in[19]};
    const float* ar[4] = {(const float*)d_in[5], (const float*)d_in[10],
                          (const float*)d_in[15], (const float*)d_in[20]};
    const float* gamma[4] = {(const float*)d_in[6], (const float*)d_in[11],
                             (const float*)d_in[16], (const float*)d_in[21]};
    const float* beta[4] = {(const float*)d_in[7], (const float*)d_in[12],
                            (const float*)d_in[17], (const float*)d_in[22]};
    const float* W_out = (const float*)d_in[23];
    const float* b_out = (const float*)d_in[24];
    float* out = (float*)d_out;

    // workspace carve
    float* wsf = (float*)d_ws;
    float* bufA = wsf;                                   // ROWS*NHD
    float* bufB = bufA + (size_t)ROWS * NHD;             // ROWS*NHD
    float* xx_cur = bufB + (size_t)ROWS * NHD;           // ROWS*NIN
    float* el = xx_cur + (size_t)ROWS * NIN;             // ROWS*NH
    float* er = el + (size_t)ROWS * NH;                  // ROWS*NH
    float* sums = er + (size_t)ROWS * NH;                // 2*NHD
    int* counts = (int*)(sums + 2 * NHD);                // NNODES
    int* offsets = counts + NNODES;                      // NNODES+1
    int* cursor = offsets + NNODES + 8;                  // NNODES
    int* csr_src = cursor + NNODES;                      // NEDGES

    // ---- CSR build (once per launch) ----
    hipMemsetAsync(counts, 0, NNODES * sizeof(int), stream);
    count_kernel<<<(NEDGES + 255) / 256, 256, 0, stream>>>(dst, counts, NEDGES);
    scan_kernel<<<1, 1024, 0, stream>>>(counts, offsets, NNODES);
    hipMemsetAsync(cursor, 0, NNODES * sizeof(int), stream);
    fill_kernel<<<(NEDGES + 255) / 256, 256, 0, stream>>>(src, dst, offsets, cursor,
                                                          csr_src, NEDGES);
    hipMemcpyAsync(xx_cur, xx, (size_t)ROWS * NIN * sizeof(float),
                   hipMemcpyDeviceToDevice, stream);

    dim3 gemm_grid(ROWS / 64, NHD / 64);
    for (int t = 0; t < NT; ++t) {
        for (int l = 0; l < 4; ++l) {
            const float* in = (l == 0) ? xx_cur : bufA;
            int K = (l == 0) ? NIN : NHD;
            gemm_kernel<<<gemm_grid, 256, 0, stream>>>(in, W[l], bufB, K);
            eler_kernel<<<ROWS, 256, 0, stream>>>(bufB, al[l], ar[l], el, er);
            attn_kernel<<<ROWS, 256, 0, stream>>>(bufB, el, er, offsets, csr_src, bufA);
            hipMemsetAsync(sums, 0, 2 * NHD * sizeof(float), stream);
            bnreduce_kernel<<<256, 256, 0, stream>>>(bufA, sums);
            bnapply_kernel<<<ROWS, 256, 0, stream>>>(bufA, sums, gamma[l], beta[l]);
        }
        headout_kernel<<<ROWS / 4, 256, 0, stream>>>(bufA, W_out, b_out, out, xx_cur, t);
    }
}

// Round 3
// 3333.097 us; speedup vs baseline: 2.1927x; 2.1927x over previous
//
#include <hip/hip_runtime.h>
#include <math.h>

#define NNODES 5000
#define NEDGES 80000
#define NB 8
#define NIN 30
#define K0PAD 32
#define NH 4
#define ND 64
#define NHD 256
#define NT 5
#define NOUT 3
#define ROWS (NB * NNODES) // 40000
#define BNEPS 1e-5f
#define MAXDEG 96
#define KP 40 // LDS k-stride (shorts), 80B rows -> 2-way bank alias (free)

typedef short shortx8 __attribute__((ext_vector_type(8)));
typedef _Float16 halfx8 __attribute__((ext_vector_type(8)));
typedef float floatx4 __attribute__((ext_vector_type(4)));

static __device__ __forceinline__ unsigned short f2h(float f) {
    union { _Float16 h; unsigned short u; } v;
    v.h = (_Float16)f;
    return v.u;
}
static __device__ __forceinline__ float h2f(unsigned short u) {
    union { _Float16 h; unsigned short u; } v;
    v.u = u;
    return (float)v.h;
}

// ---------------- CSR build ----------------

__global__ void count_kernel(const int* __restrict__ dst, int* __restrict__ counts, int n) {
    int e = blockIdx.x * blockDim.x + threadIdx.x;
    if (e < n) atomicAdd(&counts[dst[e]], 1);
}

__global__ __launch_bounds__(1024) void scan_kernel(const int* __restrict__ counts,
                                                    int* __restrict__ offsets, int n) {
    __shared__ int smem[1024];
    const int CH = 5;
    int tid = threadIdx.x;
    int base = tid * CH;
    int loc[CH];
    int s = 0;
    for (int j = 0; j < CH; ++j) {
        int i = base + j;
        int v = (i < n) ? counts[i] : 0;
        loc[j] = s;
        s += v;
    }
    smem[tid] = s;
    __syncthreads();
    for (int off = 1; off < 1024; off <<= 1) {
        int v = (tid >= off) ? smem[tid - off] : 0;
        __syncthreads();
        smem[tid] += v;
        __syncthreads();
    }
    int excl = smem[tid] - s;
    for (int j = 0; j < CH; ++j) {
        int i = base + j;
        if (i < n) offsets[i] = excl + loc[j];
    }
    if (tid == 1023) offsets[n] = smem[1023];
}

__global__ void fill_kernel(const int* __restrict__ src, const int* __restrict__ dst,
                            const int* __restrict__ offsets, int* __restrict__ cursor,
                            int* __restrict__ csr_src, int n) {
    int e = blockIdx.x * blockDim.x + threadIdx.x;
    if (e >= n) return;
    int d = dst[e];
    int pos = offsets[d] + atomicAdd(&cursor[d], 1);
    csr_src[pos] = src[e];
}

// ---------------- packing ----------------

__global__ void pack_xx_kernel(const float* __restrict__ xx, unsigned short* __restrict__ xx16) {
    int idx = blockIdx.x * blockDim.x + threadIdx.x;
    if (idx >= ROWS * K0PAD) return;
    int g = idx >> 5;
    int k = idx & 31;
    float v = (k < NIN) ? xx[(size_t)g * NIN + k] : 0.0f;
    xx16[idx] = f2h(v);
}

// Wt[n][k] = f16(W[k][n]), zero-padded to Kpad rows
__global__ void packWt_kernel(const float* __restrict__ W, unsigned short* __restrict__ Wt,
                              int Kin, int Kpad) {
    int n = blockIdx.x;
    int k = threadIdx.x;
    if (k < Kpad) {
        float v = (k < Kin) ? W[(size_t)k * NHD + n] : 0.0f;
        Wt[(size_t)n * Kpad + k] = f2h(v);
    }
}

// ---------------- MFMA GEMM + fused el/er ----------------
// C[M,256] = A[M,K] @ Wt^T.  Block: 64 rows x 256 cols, 4 waves (wave = head).
// Wave computes 4x4 tiles of 16x16 via mfma_f32_16x16x32_f16.
// Epilogue: el/er = per-head attn logits, reduced across 16 lanes.

__global__ __launch_bounds__(256) void gemm_mfma_kernel(
    const unsigned short* __restrict__ A, const unsigned short* __restrict__ Wt,
    const float* __restrict__ alw, const float* __restrict__ arw,
    float* __restrict__ C, float* __restrict__ el, float* __restrict__ er, int K) {
    __shared__ __align__(16) short As[64 * KP];
    __shared__ __align__(16) short Bs[256 * KP];
    int tid = threadIdx.x;
    int wave = tid >> 6; // head
    int lane = tid & 63;
    int c = lane & 15;
    int quad = lane >> 4;
    int row0 = blockIdx.x * 64;

    floatx4 acc[4][4];
#pragma unroll
    for (int mt = 0; mt < 4; ++mt)
#pragma unroll
        for (int nt = 0; nt < 4; ++nt) acc[mt][nt] = (floatx4){0.f, 0.f, 0.f, 0.f};

    int r = tid >> 2;
    int seg = tid & 3;
    for (int k0 = 0; k0 < K; k0 += 32) {
        // stage A tile 64x32
        {
            shortx8 v = *(const shortx8*)(A + (size_t)(row0 + r) * K + k0 + seg * 8);
            *(shortx8*)(&As[r * KP + seg * 8]) = v;
        }
        // stage B tile 256x32 (Wt is [256][K], k contiguous)
#pragma unroll
        for (int it = 0; it < 4; ++it) {
            int n = it * 64 + r;
            shortx8 v = *(const shortx8*)(Wt + (size_t)n * K + k0 + seg * 8);
            *(shortx8*)(&Bs[n * KP + seg * 8]) = v;
        }
        __syncthreads();
        halfx8 a[4], b[4];
#pragma unroll
        for (int mt = 0; mt < 4; ++mt)
            a[mt] = *(const halfx8*)(&As[(mt * 16 + c) * KP + quad * 8]);
#pragma unroll
        for (int nt = 0; nt < 4; ++nt)
            b[nt] = *(const halfx8*)(&Bs[(wave * 64 + nt * 16 + c) * KP + quad * 8]);
#pragma unroll
        for (int mt = 0; mt < 4; ++mt)
#pragma unroll
            for (int nt = 0; nt < 4; ++nt)
                acc[mt][nt] = __builtin_amdgcn_mfma_f32_16x16x32_f16(a[mt], b[nt],
                                                                     acc[mt][nt], 0, 0, 0);
        __syncthreads();
    }

    // epilogue: store C + fused el/er
    float alv[4], arv[4];
#pragma unroll
    for (int nt = 0; nt < 4; ++nt) {
        alv[nt] = alw[wave * 64 + nt * 16 + c];
        arv[nt] = arw[wave * 64 + nt * 16 + c];
    }
#pragma unroll
    for (int mt = 0; mt < 4; ++mt) {
#pragma unroll
        for (int rr = 0; rr < 4; ++rr) {
            int row = row0 + mt * 16 + quad * 4 + rr;
            float pl = 0.0f, pr = 0.0f;
#pragma unroll
            for (int nt = 0; nt < 4; ++nt) {
                float v = acc[mt][nt][rr];
                C[(size_t)row * NHD + wave * 64 + nt * 16 + c] = v;
                pl += v * alv[nt];
                pr += v * arv[nt];
            }
#pragma unroll
            for (int o = 1; o < 16; o <<= 1) {
                pl += __shfl_xor(pl, o);
                pr += __shfl_xor(pr, o);
            }
            if (c == mt * 4 + rr) {
                el[(size_t)row * NH + wave] = pl;
                er[(size_t)row * NH + wave] = pr;
            }
        }
    }
}

// ---------------- edge softmax + aggregate ----------------
// XCD swizzle: b = blk&7 so each batch's h slab pins to one XCD's L2.
// Fast path deg<=MAXDEG: LDS-cached src + softmax weights (exp computed once).

__global__ __launch_bounds__(256) void attn_kernel(const float* __restrict__ h,
                                                   const float* __restrict__ el,
                                                   const float* __restrict__ er,
                                                   const int* __restrict__ offsets,
                                                   const int* __restrict__ csr_src,
                                                   float* __restrict__ out) {
    __shared__ float w_s[NH][MAXDEG];
    __shared__ int src_s[MAXDEG];
    int blk = blockIdx.x;
    int b = blk & 7;
    int n = blk >> 3;
    int g = b * NNODES + n;
    int head = threadIdx.x >> 6;
    int lane = threadIdx.x & 63;
    int start = offsets[n];
    int end = offsets[n + 1];
    int deg = end - start;
    const float* elb = el + (size_t)b * NNODES * NH;
    float er_nh = er[(size_t)g * NH + head];

    if (deg <= MAXDEG) {
        for (int i = threadIdx.x; i < deg; i += 256) src_s[i] = csr_src[start + i];
        __syncthreads();
        float mx = -INFINITY;
        for (int i = lane; i < deg; i += 64) {
            int s = src_s[i];
            float e = elb[s * NH + head] + er_nh;
            e = (e > 0.0f) ? e : 0.2f * e;
            w_s[head][i] = e;
            mx = fmaxf(mx, e);
        }
#pragma unroll
        for (int o = 32; o; o >>= 1) mx = fmaxf(mx, __shfl_xor(mx, o));
        float sm = 0.0f;
        for (int i = lane; i < deg; i += 64) {
            float ex = __expf(w_s[head][i] - mx);
            w_s[head][i] = ex;
            sm += ex;
        }
#pragma unroll
        for (int o = 32; o; o >>= 1) sm += __shfl_xor(sm, o);
        __syncthreads();

        const float* hb = h + (size_t)b * NNODES * NHD + head * ND + lane;
        float a0 = 0.f, a1 = 0.f, a2 = 0.f, a3 = 0.f;
        int i = 0;
        for (; i + 4 <= deg; i += 4) {
            int s0 = src_s[i], s1 = src_s[i + 1], s2 = src_s[i + 2], s3 = src_s[i + 3];
            float w0 = w_s[head][i], w1 = w_s[head][i + 1];
            float w2 = w_s[head][i + 2], w3 = w_s[head][i + 3];
            a0 += w0 * hb[(size_t)s0 * NHD];
            a1 += w1 * hb[(size_t)s1 * NHD];
            a2 += w2 * hb[(size_t)s2 * NHD];
            a3 += w3 * hb[(size_t)s3 * NHD];
        }
        for (; i < deg; ++i) a0 += w_s[head][i] * hb[(size_t)src_s[i] * NHD];
        float acc = (a0 + a1) + (a2 + a3);
        float inv = (deg > 0) ? 1.0f / sm : 0.0f;
        out[(size_t)g * NHD + head * ND + lane] = acc * inv;
    } else {
        // fallback: 3-pass recompute
        float mx = -INFINITY;
        for (int i = start + lane; i < end; i += 64) {
            int s = csr_src[i];
            float e = elb[s * NH + head] + er_nh;
            e = (e > 0.0f) ? e : 0.2f * e;
            mx = fmaxf(mx, e);
        }
#pragma unroll
        for (int o = 32; o; o >>= 1) mx = fmaxf(mx, __shfl_xor(mx, o));
        float sm = 0.0f;
        for (int i = start + lane; i < end; i += 64) {
            int s = csr_src[i];
            float e = elb[s * NH + head] + er_nh;
            e = (e > 0.0f) ? e : 0.2f * e;
            sm += __expf(e - mx);
        }
#pragma unroll
        for (int o = 32; o; o >>= 1) sm += __shfl_xor(sm, o);
        const float* hb = h + (size_t)b * NNODES * NHD;
        float acc = 0.0f;
        for (int i = start; i < end; ++i) {
            int s = csr_src[i];
            float e = elb[s * NH + head] + er_nh;
            e = (e > 0.0f) ? e : 0.2f * e;
            acc += __expf(e - mx) * hb[(size_t)s * NHD + head * ND + lane];
        }
        float inv = (deg > 0) ? 1.0f / sm : 0.0f;
        out[(size_t)g * NHD + head * ND + lane] = acc * inv;
    }
}

// ---------------- BatchNorm ----------------

__global__ __launch_bounds__(256) void bnreduce_kernel(const float* __restrict__ x,
                                                       float* __restrict__ sums) {
    int c = threadIdx.x;
    float s = 0.0f, s2 = 0.0f;
    for (int row = blockIdx.x; row < ROWS; row += gridDim.x) {
        float v = x[(size_t)row * NHD + c];
        s += v;
        s2 += v * v;
    }
    atomicAdd(&sums[c], s);
    atomicAdd(&sums[NHD + c], s2);
}

// normalize + leakyrelu; writes fp32 (for attn/headout consumers) and f16 (next GEMM input)
__global__ __launch_bounds__(256) void bnapply_kernel(float* __restrict__ x,
                                                      unsigned short* __restrict__ x16,
                                                      const float* __restrict__ sums,
                                                      const float* __restrict__ gamma,
                                                      const float* __restrict__ beta) {
    int c = threadIdx.x;
    int row = blockIdx.x;
    const float invn = 1.0f / (float)ROWS;
    float mu = sums[c] * invn;
    float var = sums[NHD + c] * invn - mu * mu;
    float sc = rsqrtf(var + BNEPS) * gamma[c];
    float bt = beta[c];
    size_t idx = (size_t)row * NHD + c;
    float v = x[idx];
    v = (v - mu) * sc + bt;
    v = (v > 0.0f) ? v : 0.01f * v;
    x[idx] = v;
    x16[idx] = f2h(v);
}

// ---------------- output head + f16 window shift ----------------

__global__ __launch_bounds__(256) void headout_kernel(const float* __restrict__ x,
                                                      const float* __restrict__ Wout,
                                                      const float* __restrict__ bout,
                                                      float* __restrict__ out,
                                                      unsigned short* __restrict__ xx16, int t) {
    int wave = threadIdx.x >> 6;
    int lane = threadIdx.x & 63;
    int g = blockIdx.x * 4 + wave;
    const float* xr = x + (size_t)g * NHD;
    int c0 = lane * 4;
    float4 v = *(const float4*)(xr + c0);
    float r0 = v.x * Wout[(c0 + 0) * NOUT + 0] + v.y * Wout[(c0 + 1) * NOUT + 0] +
               v.z * Wout[(c0 + 2) * NOUT + 0] + v.w * Wout[(c0 + 3) * NOUT + 0];
    float r1 = v.x * Wout[(c0 + 0) * NOUT + 1] + v.y * Wout[(c0 + 1) * NOUT + 1] +
               v.z * Wout[(c0 + 2) * NOUT + 1] + v.w * Wout[(c0 + 3) * NOUT + 1];
    float r2 = v.x * Wout[(c0 + 0) * NOUT + 2] + v.y * Wout[(c0 + 1) * NOUT + 2] +
               v.z * Wout[(c0 + 2) * NOUT + 2] + v.w * Wout[(c0 + 3) * NOUT + 2];
#pragma unroll
    for (int o = 32; o; o >>= 1) {
        r0 += __shfl_xor(r0, o);
        r1 += __shfl_xor(r1, o);
        r2 += __shfl_xor(r2, o);
    }
    float o0 = r0 + bout[0], o1 = r1 + bout[1], o2 = r2 + bout[2];
    if (lane == 0) {
        float* op = out + ((size_t)g * NT + t) * NOUT;
        op[0] = o0;
        op[1] = o1;
        op[2] = o2;
    }
    // shift f16 input window: new[0:27] = old[3:30]; new[27:30] = out
    float oldv = (lane < NIN) ? h2f(xx16[(size_t)g * K0PAD + lane]) : 0.0f;
    float shifted = __shfl(oldv, lane + 3);
    float newv = (lane < 27) ? shifted : (lane == 27 ? o0 : (lane == 28 ? o1 : o2));
    if (lane < NIN) xx16[(size_t)g * K0PAD + lane] = f2h(newv);
}

// ---------------- launch ----------------

extern "C" void kernel_launch(void* const* d_in, const int* in_sizes, int n_in,
                              void* d_out, int out_size, void* d_ws, size_t ws_size,
                              hipStream_t stream) {
    const float* xx = (const float*)d_in[0];
    const int* src = (const int*)d_in[1];
    const int* dst = (const int*)d_in[2];
    const float* W[4] = {(const float*)d_in[3], (const float*)d_in[8],
                         (const float*)d_in[13], (const float*)d_in[18]};
    const float* al[4] = {(const float*)d_in[4], (const float*)d_in[9],
                          (const float*)d_in[14], (const float*)d_in[19]};
    const float* ar[4] = {(const float*)d_in[5], (const float*)d_in[10],
                          (const float*)d_in[15], (const float*)d_in[20]};
    const float* gamma[4] = {(const float*)d_in[6], (const float*)d_in[11],
                             (const float*)d_in[16], (const float*)d_in[21]};
    const float* beta[4] = {(const float*)d_in[7], (const float*)d_in[12],
                            (const float*)d_in[17], (const float*)d_in[22]};
    const float* W_out = (const float*)d_in[23];
    const float* b_out = (const float*)d_in[24];
    float* out = (float*)d_out;

    // workspace carve
    float* wsf = (float*)d_ws;
    float* bufA = wsf;                                     // ROWS*NHD f32
    float* bufB = bufA + (size_t)ROWS * NHD;               // ROWS*NHD f32
    float* el = bufB + (size_t)ROWS * NHD;                 // ROWS*NH
    float* er = el + (size_t)ROWS * NH;                    // ROWS*NH
    float* sums = er + (size_t)ROWS * NH;                  // 2*NHD
    unsigned short* bufA16 = (unsigned short*)(sums + 2 * NHD);   // ROWS*NHD f16
    unsigned short* xx16 = bufA16 + (size_t)ROWS * NHD;    // ROWS*K0PAD f16
    unsigned short* Wt0 = xx16 + (size_t)ROWS * K0PAD;     // 256*K0PAD
    unsigned short* Wt1 = Wt0 + 256 * K0PAD;               // 256*256
    unsigned short* Wt2 = Wt1 + 256 * NHD;
    unsigned short* Wt3 = Wt2 + 256 * NHD;
    int* counts = (int*)(Wt3 + 256 * NHD);                 // NNODES
    int* offsets = counts + NNODES;                        // NNODES+1 (+pad)
    int* cursor = offsets + NNODES + 8;                    // NNODES
    int* csr_src = cursor + NNODES;                        // NEDGES
    const unsigned short* Wt[4] = {Wt0, Wt1, Wt2, Wt3};

    // ---- CSR build + packing (once per launch) ----
    hipMemsetAsync(counts, 0, NNODES * sizeof(int), stream);
    count_kernel<<<(NEDGES + 255) / 256, 256, 0, stream>>>(dst, counts, NEDGES);
    scan_kernel<<<1, 1024, 0, stream>>>(counts, offsets, NNODES);
    hipMemsetAsync(cursor, 0, NNODES * sizeof(int), stream);
    fill_kernel<<<(NEDGES + 255) / 256, 256, 0, stream>>>(src, dst, offsets, cursor,
                                                          csr_src, NEDGES);
    pack_xx_kernel<<<(ROWS * K0PAD + 255) / 256, 256, 0, stream>>>(xx, xx16);
    packWt_kernel<<<256, 256, 0, stream>>>(W[0], Wt0, NIN, K0PAD);
    packWt_kernel<<<256, 256, 0, stream>>>(W[1], Wt1, NHD, NHD);
    packWt_kernel<<<256, 256, 0, stream>>>(W[2], Wt2, NHD, NHD);
    packWt_kernel<<<256, 256, 0, stream>>>(W[3], Wt3, NHD, NHD);

    for (int t = 0; t < NT; ++t) {
        for (int l = 0; l < 4; ++l) {
            const unsigned short* A16 = (l == 0) ? xx16 : bufA16;
            int K = (l == 0) ? K0PAD : NHD;
            gemm_mfma_kernel<<<ROWS / 64, 256, 0, stream>>>(A16, Wt[l], al[l], ar[l],
                                                            bufB, el, er, K);
            attn_kernel<<<ROWS, 256, 0, stream>>>(bufB, el, er, offsets, csr_src, bufA);
            hipMemsetAsync(sums, 0, 2 * NHD * sizeof(float), stream);
            bnreduce_kernel<<<256, 256, 0, stream>>>(bufA, sums);
            bnapply_kernel<<<ROWS, 256, 0, stream>>>(bufA, bufA16, sums, gamma[l], beta[l]);
        }
        headout_kernel<<<ROWS / 4, 256, 0, stream>>>(bufA, W_out, b_out, out, xx16, t);
    }
}

// Round 4
// 2369.206 us; speedup vs baseline: 3.0847x; 1.4068x over previous
//
#include <hip/hip_runtime.h>
#include <math.h>

#define NNODES 5000
#define NEDGES 80000
#define NB 8
#define NIN 30
#define K0PAD 32
#define NH 4
#define ND 64
#define NHD 256
#define NT 5
#define NOUT 3
#define ROWS (NB * NNODES) // 40000
#define BNEPS 1e-5f
#define MAXDEG 96
#define KP 40 // LDS k-stride (shorts), 80B rows -> 2-way bank alias (free)

typedef short shortx8 __attribute__((ext_vector_type(8)));
typedef _Float16 halfx8 __attribute__((ext_vector_type(8)));
typedef _Float16 halfx4 __attribute__((ext_vector_type(4)));
typedef _Float16 halfx2 __attribute__((ext_vector_type(2)));
typedef float floatx4 __attribute__((ext_vector_type(4)));

static __device__ __forceinline__ unsigned short f2h(float f) {
    union { _Float16 h; unsigned short u; } v;
    v.h = (_Float16)f;
    return v.u;
}
static __device__ __forceinline__ float h2f(unsigned short u) {
    union { _Float16 h; unsigned short u; } v;
    v.u = u;
    return (float)v.h;
}

// ---------------- CSR build ----------------

__global__ void count_kernel(const int* __restrict__ dst, int* __restrict__ counts, int n) {
    int e = blockIdx.x * blockDim.x + threadIdx.x;
    if (e < n) atomicAdd(&counts[dst[e]], 1);
}

__global__ __launch_bounds__(1024) void scan_kernel(const int* __restrict__ counts,
                                                    int* __restrict__ offsets, int n) {
    __shared__ int smem[1024];
    const int CH = 5;
    int tid = threadIdx.x;
    int base = tid * CH;
    int loc[CH];
    int s = 0;
    for (int j = 0; j < CH; ++j) {
        int i = base + j;
        int v = (i < n) ? counts[i] : 0;
        loc[j] = s;
        s += v;
    }
    smem[tid] = s;
    __syncthreads();
    for (int off = 1; off < 1024; off <<= 1) {
        int v = (tid >= off) ? smem[tid - off] : 0;
        __syncthreads();
        smem[tid] += v;
        __syncthreads();
    }
    int excl = smem[tid] - s;
    for (int j = 0; j < CH; ++j) {
        int i = base + j;
        if (i < n) offsets[i] = excl + loc[j];
    }
    if (tid == 1023) offsets[n] = smem[1023];
}

__global__ void fill_kernel(const int* __restrict__ src, const int* __restrict__ dst,
                            const int* __restrict__ offsets, int* __restrict__ cursor,
                            int* __restrict__ csr_src, int n) {
    int e = blockIdx.x * blockDim.x + threadIdx.x;
    if (e >= n) return;
    int d = dst[e];
    int pos = offsets[d] + atomicAdd(&cursor[d], 1);
    csr_src[pos] = src[e];
}

// ---------------- packing ----------------

__global__ void pack_xx_kernel(const float* __restrict__ xx, unsigned short* __restrict__ xx16) {
    int idx = blockIdx.x * blockDim.x + threadIdx.x;
    if (idx >= ROWS * K0PAD) return;
    int g = idx >> 5;
    int k = idx & 31;
    float v = (k < NIN) ? xx[(size_t)g * NIN + k] : 0.0f;
    xx16[idx] = f2h(v);
}

// Wt[n][k] = f16(W[k][n]), zero-padded to Kpad rows
__global__ void packWt_kernel(const float* __restrict__ W, unsigned short* __restrict__ Wt,
                              int Kin, int Kpad) {
    int n = blockIdx.x;
    int k = threadIdx.x;
    if (k < Kpad) {
        float v = (k < Kin) ? W[(size_t)k * NHD + n] : 0.0f;
        Wt[(size_t)n * Kpad + k] = f2h(v);
    }
}

// ---------------- MFMA GEMM + fused BN(prev layer) on A + fused el/er ----------------
// C16[M,256] = BNlrelu(A)[M,K] @ Wt^T.  Block: 64 rows x 256 cols, 4 waves (wave = head).
// A-staging applies x*scale[k]+shift[k] then leakyrelu(0.01) when apply_bn.
// Epilogue stores f16 h and fused per-head attn logits el/er.

__global__ __launch_bounds__(256) void gemm_mfma_kernel(
    const unsigned short* __restrict__ A, const unsigned short* __restrict__ Wt,
    const float* __restrict__ alw, const float* __restrict__ arw,
    const float* __restrict__ sums, const float* __restrict__ gamma,
    const float* __restrict__ beta, int apply_bn,
    unsigned short* __restrict__ C16, float* __restrict__ el, float* __restrict__ er,
    int K) {
    __shared__ __align__(16) short As[64 * KP];
    __shared__ __align__(16) short Bs[256 * KP];
    __shared__ float bn_scale[NHD];
    __shared__ float bn_shift[NHD];
    int tid = threadIdx.x;
    if (apply_bn) {
        int c = tid;
        const float invn = 1.0f / (float)ROWS;
        float mu = sums[c] * invn;
        float var = sums[NHD + c] * invn - mu * mu;
        float sc = rsqrtf(var + BNEPS) * gamma[c];
        bn_scale[c] = sc;
        bn_shift[c] = beta[c] - mu * sc;
    }
    __syncthreads();

    int wave = tid >> 6; // head
    int lane = tid & 63;
    int c = lane & 15;
    int quad = lane >> 4;
    int row0 = blockIdx.x * 64;

    floatx4 acc[4][4];
#pragma unroll
    for (int mt = 0; mt < 4; ++mt)
#pragma unroll
        for (int nt = 0; nt < 4; ++nt) acc[mt][nt] = (floatx4){0.f, 0.f, 0.f, 0.f};

    int r = tid >> 2;
    int seg = tid & 3;
    for (int k0 = 0; k0 < K; k0 += 32) {
        // stage A tile 64x32 (+ fused BN + leakyrelu)
        {
            shortx8 v = *(const shortx8*)(A + (size_t)(row0 + r) * K + k0 + seg * 8);
            if (apply_bn) {
                halfx8 hv = *(halfx8*)&v;
                int kg = k0 + seg * 8;
#pragma unroll
                for (int j = 0; j < 8; ++j) {
                    float x = (float)hv[j];
                    x = fmaf(x, bn_scale[kg + j], bn_shift[kg + j]);
                    x = (x > 0.0f) ? x : 0.01f * x;
                    hv[j] = (_Float16)x;
                }
                v = *(shortx8*)&hv;
            }
            *(shortx8*)(&As[r * KP + seg * 8]) = v;
        }
        // stage B tile 256x32 (Wt is [256][K], k contiguous)
#pragma unroll
        for (int it = 0; it < 4; ++it) {
            int n = it * 64 + r;
            shortx8 v = *(const shortx8*)(Wt + (size_t)n * K + k0 + seg * 8);
            *(shortx8*)(&Bs[n * KP + seg * 8]) = v;
        }
        __syncthreads();
        halfx8 a[4], b[4];
#pragma unroll
        for (int mt = 0; mt < 4; ++mt)
            a[mt] = *(const halfx8*)(&As[(mt * 16 + c) * KP + quad * 8]);
#pragma unroll
        for (int nt = 0; nt < 4; ++nt)
            b[nt] = *(const halfx8*)(&Bs[(wave * 64 + nt * 16 + c) * KP + quad * 8]);
#pragma unroll
        for (int mt = 0; mt < 4; ++mt)
#pragma unroll
            for (int nt = 0; nt < 4; ++nt)
                acc[mt][nt] = __builtin_amdgcn_mfma_f32_16x16x32_f16(a[mt], b[nt],
                                                                     acc[mt][nt], 0, 0, 0);
        __syncthreads();
    }

    // epilogue: store f16 C + fused el/er
    float alv[4], arv[4];
#pragma unroll
    for (int nt = 0; nt < 4; ++nt) {
        alv[nt] = alw[wave * 64 + nt * 16 + c];
        arv[nt] = arw[wave * 64 + nt * 16 + c];
    }
#pragma unroll
    for (int mt = 0; mt < 4; ++mt) {
#pragma unroll
        for (int rr = 0; rr < 4; ++rr) {
            int row = row0 + mt * 16 + quad * 4 + rr;
            float pl = 0.0f, pr = 0.0f;
#pragma unroll
            for (int nt = 0; nt < 4; ++nt) {
                float v = acc[mt][nt][rr];
                C16[(size_t)row * NHD + wave * 64 + nt * 16 + c] = f2h(v);
                pl += v * alv[nt];
                pr += v * arv[nt];
            }
#pragma unroll
            for (int o = 1; o < 16; o <<= 1) {
                pl += __shfl_xor(pl, o);
                pr += __shfl_xor(pr, o);
            }
            if (c == mt * 4 + rr) {
                el[(size_t)row * NH + wave] = pl;
                er[(size_t)row * NH + wave] = pr;
            }
        }
    }
}

// ---------------- edge softmax + aggregate (f16 gather, 2 nodes/block) ----------------
// Block = 256 thr: node = tid>>7 (2 nodes), wave-half (32 lanes) = one head.
// Lane covers 2 channels via packed halfx2. XCD swizzle: b = blk&7.

__global__ __launch_bounds__(256) void attn_kernel(const unsigned short* __restrict__ h16,
                                                   const float* __restrict__ el,
                                                   const float* __restrict__ er,
                                                   const int* __restrict__ offsets,
                                                   const int* __restrict__ csr_src,
                                                   unsigned short* __restrict__ out16) {
    __shared__ int src_s[2][MAXDEG];
    __shared__ float w_s[2][NH][MAXDEG];
    int p = blockIdx.x;
    int b = p & 7;
    int n2 = p >> 3; // 0..2499
    int tid = threadIdx.x;
    int nn = tid >> 7; // node within pair
    int n = n2 * 2 + nn;
    int g = b * NNODES + n;
    int lane = tid & 63;
    int head = ((tid >> 6) & 1) * 2 + (lane >> 5);
    int l32 = lane & 31;
    int start = offsets[n];
    int end = offsets[n + 1];
    int deg = end - start;
    const float* elb = el + (size_t)b * NNODES * NH;
    float er_nh = er[(size_t)g * NH + head];
    bool fast = (deg <= MAXDEG);

    if (fast)
        for (int i = (tid & 127); i < deg; i += 128) src_s[nn][i] = csr_src[start + i];
    __syncthreads();

    const unsigned short* hb = h16 + (size_t)b * NNODES * NHD + head * ND + l32 * 2;
    if (fast) {
        float mx = -INFINITY;
        for (int i = l32; i < deg; i += 32) {
            float e = elb[src_s[nn][i] * NH + head] + er_nh;
            e = (e > 0.0f) ? e : 0.2f * e;
            w_s[nn][head][i] = e;
            mx = fmaxf(mx, e);
        }
#pragma unroll
        for (int o = 16; o; o >>= 1) mx = fmaxf(mx, __shfl_xor(mx, o));
        float sm = 0.0f;
        for (int i = l32; i < deg; i += 32) {
            float ex = __expf(w_s[nn][head][i] - mx);
            w_s[nn][head][i] = ex;
            sm += ex;
        }
#pragma unroll
        for (int o = 16; o; o >>= 1) sm += __shfl_xor(sm, o);
        // w_s[nn][head] written & read by the same 32 lanes -> no barrier needed

        float ax0 = 0.f, ay0 = 0.f, ax1 = 0.f, ay1 = 0.f;
        int i = 0;
        for (; i + 2 <= deg; i += 2) {
            int s0 = src_s[nn][i], s1 = src_s[nn][i + 1];
            float w0 = w_s[nn][head][i], w1 = w_s[nn][head][i + 1];
            halfx2 h0 = *(const halfx2*)(hb + (size_t)s0 * NHD);
            halfx2 h1 = *(const halfx2*)(hb + (size_t)s1 * NHD);
            ax0 += w0 * (float)h0.x;
            ay0 += w0 * (float)h0.y;
            ax1 += w1 * (float)h1.x;
            ay1 += w1 * (float)h1.y;
        }
        if (i < deg) {
            float w0 = w_s[nn][head][i];
            halfx2 h0 = *(const halfx2*)(hb + (size_t)src_s[nn][i] * NHD);
            ax0 += w0 * (float)h0.x;
            ay0 += w0 * (float)h0.y;
        }
        float inv = (deg > 0) ? 1.0f / sm : 0.0f;
        halfx2 o2;
        o2.x = (_Float16)((ax0 + ax1) * inv);
        o2.y = (_Float16)((ay0 + ay1) * inv);
        *(halfx2*)(out16 + (size_t)g * NHD + head * ND + l32 * 2) = o2;
    } else {
        // fallback: 3-pass recompute from CSR
        float mx = -INFINITY;
        for (int i = start + l32; i < end; i += 32) {
            float e = elb[csr_src[i] * NH + head] + er_nh;
            e = (e > 0.0f) ? e : 0.2f * e;
            mx = fmaxf(mx, e);
        }
#pragma unroll
        for (int o = 16; o; o >>= 1) mx = fmaxf(mx, __shfl_xor(mx, o));
        float sm = 0.0f;
        for (int i = start + l32; i < end; i += 32) {
            float e = elb[csr_src[i] * NH + head] + er_nh;
            e = (e > 0.0f) ? e : 0.2f * e;
            sm += __expf(e - mx);
        }
#pragma unroll
        for (int o = 16; o; o >>= 1) sm += __shfl_xor(sm, o);
        float ax = 0.f, ay = 0.f;
        for (int i = start; i < end; ++i) {
            int s = csr_src[i];
            float e = elb[s * NH + head] + er_nh;
            e = (e > 0.0f) ? e : 0.2f * e;
            float w = __expf(e - mx);
            halfx2 hv = *(const halfx2*)(hb + (size_t)s * NHD);
            ax += w * (float)hv.x;
            ay += w * (float)hv.y;
        }
        float inv = (deg > 0) ? 1.0f / sm : 0.0f;
        halfx2 o2;
        o2.x = (_Float16)(ax * inv);
        o2.y = (_Float16)(ay * inv);
        *(halfx2*)(out16 + (size_t)g * NHD + head * ND + l32 * 2) = o2;
    }
}

// ---------------- BatchNorm stats from f16 activations ----------------
// thread -> channel pair (halfx2); 512 row-streams; 4 atomics/thread.

__global__ __launch_bounds__(256) void bnreduce_kernel(const unsigned short* __restrict__ x16,
                                                       float* __restrict__ sums) {
    int tid = threadIdx.x;
    int c2 = (tid & 127) * 2;
    int rhalf = tid >> 7;
    float sx = 0.f, sx2 = 0.f, sy = 0.f, sy2 = 0.f;
    for (int row = blockIdx.x * 2 + rhalf; row < ROWS; row += 512) {
        halfx2 hv = *(const halfx2*)(x16 + (size_t)row * NHD + c2);
        float vx = (float)hv.x, vy = (float)hv.y;
        sx += vx;
        sx2 += vx * vx;
        sy += vy;
        sy2 += vy * vy;
    }
    atomicAdd(&sums[c2], sx);
    atomicAdd(&sums[c2 + 1], sy);
    atomicAdd(&sums[NHD + c2], sx2);
    atomicAdd(&sums[NHD + c2 + 1], sy2);
}

// ---------------- output head (inline BN+lrelu) + f16 window shift ----------------

__global__ __launch_bounds__(256) void headout_kernel(const unsigned short* __restrict__ x16,
                                                      const float* __restrict__ sums,
                                                      const float* __restrict__ gamma,
                                                      const float* __restrict__ beta,
                                                      const float* __restrict__ Wout,
                                                      const float* __restrict__ bout,
                                                      float* __restrict__ out,
                                                      unsigned short* __restrict__ xx16, int t) {
    int wave = threadIdx.x >> 6;
    int lane = threadIdx.x & 63;
    int g = blockIdx.x * 4 + wave;
    int c0 = lane * 4;
    halfx4 hv = *(const halfx4*)(x16 + (size_t)g * NHD + c0);
    const float invn = 1.0f / (float)ROWS;
    float vv[4];
#pragma unroll
    for (int j = 0; j < 4; ++j) {
        int c = c0 + j;
        float mu = sums[c] * invn;
        float var = sums[NHD + c] * invn - mu * mu;
        float sc = rsqrtf(var + BNEPS) * gamma[c];
        float x = fmaf((float)hv[j], sc, beta[c] - mu * sc);
        vv[j] = (x > 0.0f) ? x : 0.01f * x;
    }
    float r0 = vv[0] * Wout[(c0 + 0) * NOUT + 0] + vv[1] * Wout[(c0 + 1) * NOUT + 0] +
               vv[2] * Wout[(c0 + 2) * NOUT + 0] + vv[3] * Wout[(c0 + 3) * NOUT + 0];
    float r1 = vv[0] * Wout[(c0 + 0) * NOUT + 1] + vv[1] * Wout[(c0 + 1) * NOUT + 1] +
               vv[2] * Wout[(c0 + 2) * NOUT + 1] + vv[3] * Wout[(c0 + 3) * NOUT + 1];
    float r2 = vv[0] * Wout[(c0 + 0) * NOUT + 2] + vv[1] * Wout[(c0 + 1) * NOUT + 2] +
               vv[2] * Wout[(c0 + 2) * NOUT + 2] + vv[3] * Wout[(c0 + 3) * NOUT + 2];
#pragma unroll
    for (int o = 32; o; o >>= 1) {
        r0 += __shfl_xor(r0, o);
        r1 += __shfl_xor(r1, o);
        r2 += __shfl_xor(r2, o);
    }
    float o0 = r0 + bout[0], o1 = r1 + bout[1], o2 = r2 + bout[2];
    if (lane == 0) {
        float* op = out + ((size_t)g * NT + t) * NOUT;
        op[0] = o0;
        op[1] = o1;
        op[2] = o2;
    }
    // shift f16 input window: new[0:27] = old[3:30]; new[27:30] = out
    float oldv = (lane < NIN) ? h2f(xx16[(size_t)g * K0PAD + lane]) : 0.0f;
    float shifted = __shfl(oldv, lane + 3);
    float newv = (lane < 27) ? shifted : (lane == 27 ? o0 : (lane == 28 ? o1 : o2));
    if (lane < NIN) xx16[(size_t)g * K0PAD + lane] = f2h(newv);
}

// ---------------- launch ----------------

extern "C" void kernel_launch(void* const* d_in, const int* in_sizes, int n_in,
                              void* d_out, int out_size, void* d_ws, size_t ws_size,
                              hipStream_t stream) {
    const float* xx = (const float*)d_in[0];
    const int* src = (const int*)d_in[1];
    const int* dst = (const int*)d_in[2];
    const float* W[4] = {(const float*)d_in[3], (const float*)d_in[8],
                         (const float*)d_in[13], (const float*)d_in[18]};
    const float* al[4] = {(const float*)d_in[4], (const float*)d_in[9],
                          (const float*)d_in[14], (const float*)d_in[19]};
    const float* ar[4] = {(const float*)d_in[5], (const float*)d_in[10],
                          (const float*)d_in[15], (const float*)d_in[20]};
    const float* gamma[4] = {(const float*)d_in[6], (const float*)d_in[11],
                             (const float*)d_in[16], (const float*)d_in[21]};
    const float* beta[4] = {(const float*)d_in[7], (const float*)d_in[12],
                            (const float*)d_in[17], (const float*)d_in[22]};
    const float* W_out = (const float*)d_in[23];
    const float* b_out = (const float*)d_in[24];
    float* out = (float*)d_out;

    // workspace carve
    float* wsf = (float*)d_ws;
    float* el = wsf;                                        // ROWS*NH
    float* er = el + (size_t)ROWS * NH;                     // ROWS*NH
    float* sums = er + (size_t)ROWS * NH;                   // 2*NHD
    unsigned short* h16 = (unsigned short*)(sums + 2 * NHD);  // ROWS*NHD (gemm out)
    unsigned short* act16 = h16 + (size_t)ROWS * NHD;       // ROWS*NHD (attn out)
    unsigned short* xx16 = act16 + (size_t)ROWS * NHD;      // ROWS*K0PAD
    unsigned short* Wt0 = xx16 + (size_t)ROWS * K0PAD;      // 256*K0PAD
    unsigned short* Wt1 = Wt0 + 256 * K0PAD;                // 256*256
    unsigned short* Wt2 = Wt1 + 256 * NHD;
    unsigned short* Wt3 = Wt2 + 256 * NHD;
    int* counts = (int*)(Wt3 + 256 * NHD);                  // NNODES
    int* offsets = counts + NNODES;                         // NNODES+1 (+pad)
    int* cursor = offsets + NNODES + 8;                     // NNODES
    int* csr_src = cursor + NNODES;                         // NEDGES
    const unsigned short* Wt[4] = {Wt0, Wt1, Wt2, Wt3};

    // ---- CSR build + packing (once per launch) ----
    hipMemsetAsync(counts, 0, NNODES * sizeof(int), stream);
    count_kernel<<<(NEDGES + 255) / 256, 256, 0, stream>>>(dst, counts, NEDGES);
    scan_kernel<<<1, 1024, 0, stream>>>(counts, offsets, NNODES);
    hipMemsetAsync(cursor, 0, NNODES * sizeof(int), stream);
    fill_kernel<<<(NEDGES + 255) / 256, 256, 0, stream>>>(src, dst, offsets, cursor,
                                                          csr_src, NEDGES);
    pack_xx_kernel<<<(ROWS * K0PAD + 255) / 256, 256, 0, stream>>>(xx, xx16);
    packWt_kernel<<<256, 256, 0, stream>>>(W[0], Wt0, NIN, K0PAD);
    packWt_kernel<<<256, 256, 0, stream>>>(W[1], Wt1, NHD, NHD);
    packWt_kernel<<<256, 256, 0, stream>>>(W[2], Wt2, NHD, NHD);
    packWt_kernel<<<256, 256, 0, stream>>>(W[3], Wt3, NHD, NHD);

    for (int t = 0; t < NT; ++t) {
        for (int l = 0; l < 4; ++l) {
            const unsigned short* A16 = (l == 0) ? xx16 : act16;
            int K = (l == 0) ? K0PAD : NHD;
            int apply_bn = (l > 0) ? 1 : 0;
            const float* pg = gamma[(l > 0) ? l - 1 : 0];
            const float* pb = beta[(l > 0) ? l - 1 : 0];
            gemm_mfma_kernel<<<ROWS / 64, 256, 0, stream>>>(A16, Wt[l], al[l], ar[l],
                                                            sums, pg, pb, apply_bn,
                                                            h16, el, er, K);
            attn_kernel<<<ROWS / 2, 256, 0, stream>>>(h16, el, er, offsets, csr_src, act16);
            hipMemsetAsync(sums, 0, 2 * NHD * sizeof(float), stream);
            bnreduce_kernel<<<256, 256, 0, stream>>>(act16, sums);
        }
        headout_kernel<<<ROWS / 4, 256, 0, stream>>>(act16, sums, gamma[3], beta[3],
                                                     W_out, b_out, out, xx16, t);
    }
}